// Round 21
// baseline (106.058 us; speedup 1.0000x reference)
//
#include <hip/hip_runtime.h>
#include <hip/hip_bf16.h>

typedef __attribute__((ext_vector_type(8))) short bf16x8;
typedef __attribute__((ext_vector_type(8))) unsigned short ushort8;
typedef __attribute__((ext_vector_type(4))) float f32x4;
typedef __attribute__((ext_vector_type(16))) float f32x16;

typedef const __attribute__((address_space(1))) void gvoid;
typedef __attribute__((address_space(3))) void svoid;

__device__ __forceinline__ unsigned short f2bf(float f) {
  union { float f; unsigned int u; } v; v.f = f;
  unsigned int u = v.u;
  unsigned int r = (u + 0x7fffu + ((u >> 16) & 1u)) >> 16;
  return (unsigned short)r;
}
__device__ __forceinline__ float bf2f(unsigned short u) {
  union { unsigned int i; float f; } v; v.i = ((unsigned int)u) << 16; return v.f;
}

// ---------------- fused fp32 -> bf16 cast for all three inputs ----------------
__global__ void cast3_kernel(const float* __restrict__ a, int na4,
                             const float* __restrict__ b, int nb4,
                             const float* __restrict__ c, int nc4,
                             unsigned short* __restrict__ oa,
                             unsigned short* __restrict__ ob,
                             unsigned short* __restrict__ oc) {
  const int total = na4 + nb4 + nc4;
  for (int i = blockIdx.x * 256 + threadIdx.x; i < total; i += gridDim.x * 256) {
    const float* src; unsigned short* dst; int j = i;
    if (j < na4) { src = a; dst = oa; }
    else if (j < na4 + nb4) { j -= na4; src = b; dst = ob; }
    else { j -= na4 + nb4; src = c; dst = oc; }
    const float4 v = reinterpret_cast<const float4*>(src)[j];
    ushort4 o4;
    o4.x = f2bf(v.x); o4.y = f2bf(v.y); o4.z = f2bf(v.z); o4.w = f2bf(v.w);
    reinterpret_cast<ushort4*>(dst)[j] = o4;
  }
}

// ---------------- C[M][N] = A[M][K] * B[N][K]^T, bf16 in, fp32 acc ----------------
// 128x128 2-phase double-buffered, ROUND-21: counted-vmcnt pipeline. The old
// __syncthreads carried an implicit s_waitcnt vmcnt(0) that drained the 4
// just-issued loads every K-step (the documented ~20% m97-structure stall).
// New protocol per K-step: issue next tile's 4 global_load_lds -> vmcnt(4)
// (waits only for CUR's 4; per-wave counts + barrier cover the block) ->
// s_barrier -> compute -> lgkmcnt(0) + s_barrier (reads done before overwrite).
// The 4 new loads stay in flight across compute AND both barriers.
template<bool OUT_BF16>
__global__ __launch_bounds__(256) void gemm_bt(const unsigned short* __restrict__ A,
                                               const unsigned short* __restrict__ B,
                                               void* __restrict__ Cv,
                                               int M, int N, int K,
                                               float qscale, int qcols) {
  constexpr int BM = 128, BK = 32, TILE = BM * BK;
  __shared__ alignas(16) unsigned short As[2 * TILE];
  __shared__ alignas(16) unsigned short Bs[2 * TILE];
  const int tid = threadIdx.x;
  const int l  = tid & 63;
  const int w  = tid >> 6;
  const int wr = w >> 1, wc = w & 1;
  const int lr = l & 15, lg = l >> 4;
  const long tile_m = (long)blockIdx.x * BM;
  const long tile_n = (long)blockIdx.y * BM;

  const int c0 = tid, c1 = tid + 256;
  const unsigned short* pa0 = A + (tile_m + (c0 >> 2)) * (long)K + (c0 & 3) * 8;
  const unsigned short* pa1 = A + (tile_m + (c1 >> 2)) * (long)K + (c1 & 3) * 8;
  const unsigned short* pb0 = B + (tile_n + (c0 >> 2)) * (long)K + (c0 & 3) * 8;
  const unsigned short* pb1 = B + (tile_n + (c1 >> 2)) * (long)K + (c1 & 3) * 8;
  const int woff = w * 512;

  f32x4 acc[4][4] = {};
  const int NT = K / BK;

#define STAGE4(Abase, Bbase, ko)                                                                 \
  {                                                                                              \
    __builtin_amdgcn_global_load_lds((gvoid*)(pa0 + (ko)), (svoid*)((Abase) + woff), 16, 0, 0);  \
    __builtin_amdgcn_global_load_lds((gvoid*)(pa1 + (ko)), (svoid*)((Abase) + 2048 + woff), 16, 0, 0); \
    __builtin_amdgcn_global_load_lds((gvoid*)(pb0 + (ko)), (svoid*)((Bbase) + woff), 16, 0, 0);  \
    __builtin_amdgcn_global_load_lds((gvoid*)(pb1 + (ko)), (svoid*)((Bbase) + 2048 + woff), 16, 0, 0); \
  }

  STAGE4(As, Bs, 0);                       // prologue: tile 0 -> buf 0
  int cur = 0;
  for (int kt = 0; kt < NT; ++kt) {
    if (kt + 1 < NT) {
      unsigned short* An = As + (cur ^ 1) * TILE;
      unsigned short* Bn = Bs + (cur ^ 1) * TILE;
      STAGE4(An, Bn, (kt + 1) * BK);       // next tile; flies across compute
      asm volatile("s_waitcnt vmcnt(4)" ::: "memory");   // cur's 4 landed (per wave)
    } else {
      asm volatile("s_waitcnt vmcnt(0)" ::: "memory");
    }
    __builtin_amdgcn_s_barrier();          // cur staged block-wide
    __builtin_amdgcn_sched_barrier(0);

    const unsigned short* AsC = As + cur * TILE;
    const unsigned short* BsC = Bs + cur * TILE;
    bf16x8 af[4], bfr[4];
#pragma unroll
    for (int m = 0; m < 4; ++m)
      af[m] = *reinterpret_cast<const bf16x8*>(AsC + (wr * 64 + m * 16 + lr) * BK + lg * 8);
#pragma unroll
    for (int n = 0; n < 4; ++n)
      bfr[n] = *reinterpret_cast<const bf16x8*>(BsC + (wc * 64 + n * 16 + lr) * BK + lg * 8);
#pragma unroll
    for (int m = 0; m < 4; ++m)
#pragma unroll
      for (int n = 0; n < 4; ++n)
        acc[m][n] = __builtin_amdgcn_mfma_f32_16x16x32_bf16(af[m], bfr[n], acc[m][n], 0, 0, 0);

    asm volatile("s_waitcnt lgkmcnt(0)" ::: "memory");   // own LDS reads drained
    __builtin_amdgcn_s_barrier();          // all waves done reading cur
    __builtin_amdgcn_sched_barrier(0);
    cur ^= 1;
  }
#undef STAGE4

#pragma unroll
  for (int m = 0; m < 4; ++m)
#pragma unroll
    for (int n = 0; n < 4; ++n)
#pragma unroll
      for (int r = 0; r < 4; ++r) {
        long row = tile_m + wr * 64 + m * 16 + lg * 4 + r;
        long col = tile_n + wc * 64 + n * 16 + lr;
        float sc = (col < qcols) ? qscale : 1.0f;
        if (OUT_BF16)
          reinterpret_cast<unsigned short*>(Cv)[row * N + col] = f2bf(acc[m][n][r] * sc);
        else
          reinterpret_cast<float*>(Cv)[row * N + col] = acc[m][n][r] * sc;
      }
}

// ---------------- causal flash attention: balanced KV-chunk jobs (r15) --------
// 768 blocks x 256 threads. Job table: qtb 8..15 split into 2 KV chunks
// (partials merged by merge_kernel); qtb 0..7 whole. Swapped QK^T
// (mfma_32x32x16, A=K, B=Q) -> in-lane softmax + one shfl_xor(32);
// P->A-frags via v_cvt_pk_bf16_f32 + v_permlane32_swap; defer-max THR=8;
// wave-uniform needMask branch-hoist; s_setprio(1) around MFMA clusters.
// Q pre-scaled 0.125 in GEMM1 epilogue. K_lds slot^=k&7; Vt slot^=(d^(d>>3))&7.
__global__ __launch_bounds__(256, 2) void attn_kernel(const unsigned short* __restrict__ qkv,
                                                      unsigned short* __restrict__ o,
                                                      unsigned short* __restrict__ Opart,
                                                      float* __restrict__ mpart,
                                                      float* __restrict__ lpart) {
  constexpr int E = 3072, T = 2048;
  __shared__ alignas(16) unsigned short Ks[64 * 64];   // [k][d], slot ^= k&7
  __shared__ alignas(16) unsigned short Vt[64 * 64];   // [d][k], slot ^= (d^(d>>3))&7
  __shared__ float alBuf[4][32];

  static const int jq[24]  = {15,15, 7,14,14,13,13, 6,12,12,11,11, 5,10,10, 9, 9, 4, 8, 8, 3, 2, 1, 0};
  static const int jt0[24] = { 0,16, 0, 0,15, 0,14, 0, 0,13, 0,12, 0, 0,11, 0,10, 0, 0, 9, 0, 0, 0, 0};
  static const int jt1[24] = {16,32,16,15,30,14,28,14,13,26,12,24,12,11,22,10,20,10, 9,18, 8, 6, 4, 2};

  const int tid = threadIdx.x;
  const int l = tid & 63, w = tid >> 6;
  const int hh = l >> 5;       // lane half
  const int lc = l & 31;       // lane col: q-row (softmax) / d-col (O)
  int jj = blockIdx.x >> 5;
  if (jj >= 8 && jj < 16) jj = 23 - jj;     // reverse middle third for balance
  const int bh = blockIdx.x & 31;
  const int qtb = jq[jj], t0 = jt0[jj], t1 = jt1[jj];
  const bool isSplit = (qtb >= 8);
  const int part = (t0 != 0) ? 1 : 0;
  const int pidx = (((bh << 3) + (qtb - 8)) << 1) + part;
  const int b = bh >> 4, hd = bh & 15;
  const unsigned short* Qb = qkv + (size_t)b * T * E + hd * 64;
  const unsigned short* Kb = Qb + 1024;
  const unsigned short* Vb = Qb + 2048;

  const int qrow0 = qtb * 128 + w * 32;
  const int qg = qrow0 + lc;       // lane's q-row (global)

  // staging duty: 256 threads, 2 chunks each (rows 0..31 and 32..63)
  const int kr0 = tid >> 3, js0 = tid & 7;
  const int kr1 = kr0 + 32;
  const unsigned short* sK = Kb + (size_t)kr0 * E + js0 * 8;
  const unsigned short* sV = Vb + (size_t)kr0 * E + js0 * 8;
  const size_t tileStep = (size_t)64 * E;

  // Q fragments (B-operand): col=lc=q, k(d) = 16c + 8*hh + j
  bf16x8 aq[4];
#pragma unroll
  for (int c = 0; c < 4; ++c)
    aq[c] = *reinterpret_cast<const bf16x8*>(Qb + (size_t)qg * E + c * 16 + hh * 8);

  f32x16 accO0 = {}, accO1 = {};   // O[q][d]: frag0 d=lc, frag1 d=32+lc
  float mL = -1e30f, ls = 0.f;

  // prologue: tile t0 into regs
  ushort8 k0 = *reinterpret_cast<const ushort8*>(sK + (size_t)t0 * tileStep);
  ushort8 k1 = *reinterpret_cast<const ushort8*>(sK + (size_t)t0 * tileStep + 32 * E);
  ushort8 v0 = *reinterpret_cast<const ushort8*>(sV + (size_t)t0 * tileStep);
  ushort8 v1 = *reinterpret_cast<const ushort8*>(sV + (size_t)t0 * tileStep + 32 * E);

  for (int t = t0; t < t1; ++t) {
    __syncthreads();   // all waves done reading previous tile
    *reinterpret_cast<ushort8*>(Ks + kr0 * 64 + ((js0 ^ (kr0 & 7)) << 3)) = k0;
    *reinterpret_cast<ushort8*>(Ks + kr1 * 64 + ((js0 ^ (kr1 & 7)) << 3)) = k1;
#pragma unroll
    for (int e = 0; e < 8; ++e) {
      int d = js0 * 8 + e;
      int swz = (d ^ (d >> 3)) & 7;
      Vt[d * 64 + ((((kr0 >> 3) ^ swz) << 3) | (kr0 & 7))] = (unsigned short)v0[e];
      Vt[d * 64 + ((((kr1 >> 3) ^ swz) << 3) | (kr1 & 7))] = (unsigned short)v1[e];
    }
    __syncthreads();   // staging visible
    if (t + 1 < t1) {  // prefetch next tile into regs (lands during compute)
      const unsigned short* nK = sK + (size_t)(t + 1) * tileStep;
      const unsigned short* nV = sV + (size_t)(t + 1) * tileStep;
      k0 = *reinterpret_cast<const ushort8*>(nK);
      k1 = *reinterpret_cast<const ushort8*>(nK + 32 * E);
      v0 = *reinterpret_cast<const ushort8*>(nV);
      v1 = *reinterpret_cast<const ushort8*>(nV + 32 * E);
    }

    if (t * 64 > qrow0 + 31) continue;   // wave-uniform: tile fully masked

    // ---- S^T = K · Q^T : D[k][q], 2 frags (k 0..31, 32..63) ----
    f32x16 sT0 = {}, sT1 = {};
    __builtin_amdgcn_s_setprio(1);
#pragma unroll
    for (int c = 0; c < 4; ++c) {
      int sl = ((2 * c + hh) ^ (lc & 7)) << 3;
      bf16x8 ak0 = *reinterpret_cast<const bf16x8*>(Ks + lc * 64 + sl);
      bf16x8 ak1 = *reinterpret_cast<const bf16x8*>(Ks + (32 + lc) * 64 + sl);
      sT0 = __builtin_amdgcn_mfma_f32_32x32x16_bf16(ak0, aq[c], sT0, 0, 0, 0);
      sT1 = __builtin_amdgcn_mfma_f32_32x32x16_bf16(ak1, aq[c], sT1, 0, 0, 0);
    }
    __builtin_amdgcn_s_setprio(0);

    // ---- causal mask (wave-uniform branch) + row max ----
    const bool needMask = (t * 64 + 63) > qrow0;   // max_k vs wave's MIN q-row
    float pm = -1e30f;
    if (needMask) {
#pragma unroll
      for (int r = 0; r < 16; ++r) {
        int kb = t * 64 + (r & 3) + 8 * (r >> 2) + 4 * hh;
        float a0 = sT0[r], a1 = sT1[r];
        if (kb > qg) a0 = -1e30f;
        if (kb + 32 > qg) a1 = -1e30f;
        sT0[r] = a0; sT1[r] = a1;
        pm = fmaxf(pm, fmaxf(a0, a1));
      }
    } else {
#pragma unroll
      for (int r = 0; r < 16; ++r)
        pm = fmaxf(pm, fmaxf(sT0[r], sT1[r]));
    }
    pm = fmaxf(pm, __shfl_xor(pm, 32));   // lane pair shares the q-row

    // ---- defer-max (THR=8) ----
    if (__any(pm > mL + 8.f)) {
      float mn = fmaxf(mL, pm);
      float al = __expf(mL - mn);
      mL = mn;
      ls *= al;
      alBuf[w][lc] = al;
      asm volatile("s_waitcnt lgkmcnt(0)" ::: "memory");
      __builtin_amdgcn_sched_barrier(0);
#pragma unroll
      for (int r = 0; r < 16; ++r) {
        float alr = alBuf[w][(r & 3) + 8 * (r >> 2) + 4 * hh];
        accO0[r] *= alr;
        accO1[r] *= alr;
      }
    }

    // ---- P = exp(S-m); A-frags via cvt_pk + permlane32_swap ----
    bf16x8 pa[4];
    union U4 { unsigned int u[4]; bf16x8 v; };
#pragma unroll
    for (int n = 0; n < 2; ++n) {
      float p[16];
#pragma unroll
      for (int r = 0; r < 16; ++r) {
        float pv = __expf((n ? sT1[r] : sT0[r]) - mL);
        p[r] = pv;
        ls += pv;
      }
#pragma unroll
      for (int gg = 0; gg < 2; ++gg) {     // frag c' = 2n + gg, from p[8gg..8gg+7]
        unsigned int x0, x1, y0, y1;
        asm("v_cvt_pk_bf16_f32 %0, %1, %2" : "=v"(x0) : "v"(p[8 * gg + 0]), "v"(p[8 * gg + 1]));
        asm("v_cvt_pk_bf16_f32 %0, %1, %2" : "=v"(x1) : "v"(p[8 * gg + 2]), "v"(p[8 * gg + 3]));
        asm("v_cvt_pk_bf16_f32 %0, %1, %2" : "=v"(y0) : "v"(p[8 * gg + 4]), "v"(p[8 * gg + 5]));
        asm("v_cvt_pk_bf16_f32 %0, %1, %2" : "=v"(y1) : "v"(p[8 * gg + 6]), "v"(p[8 * gg + 7]));
        asm("v_permlane32_swap_b32 %0, %1" : "+v"(x0), "+v"(y0));
        asm("v_permlane32_swap_b32 %0, %1" : "+v"(x1), "+v"(y1));
        U4 fu;
        fu.u[0] = x0; fu.u[1] = x1; fu.u[2] = y0; fu.u[3] = y1;
        pa[2 * n + gg] = fu.v;
      }
    }

    // ---- O += P V : B[k][d] from Vt; frag m: d = 32m + lc ----
    __builtin_amdgcn_s_setprio(1);
#pragma unroll
    for (int cp = 0; cp < 4; ++cp) {
      int d0 = lc, d1 = 32 + lc;
      int sl0 = ((2 * cp + hh) ^ ((d0 ^ (d0 >> 3)) & 7)) << 3;
      int sl1 = ((2 * cp + hh) ^ ((d1 ^ (d1 >> 3)) & 7)) << 3;
      bf16x8 bv0 = *reinterpret_cast<const bf16x8*>(Vt + d0 * 64 + sl0);
      bf16x8 bv1 = *reinterpret_cast<const bf16x8*>(Vt + d1 * 64 + sl1);
      accO0 = __builtin_amdgcn_mfma_f32_32x32x16_bf16(pa[cp], bv0, accO0, 0, 0, 0);
      accO1 = __builtin_amdgcn_mfma_f32_32x32x16_bf16(pa[cp], bv1, accO1, 0, 0, 0);
    }
    __builtin_amdgcn_s_setprio(0);
  } // t

  // ---- finalize ----
  float lsT = ls + __shfl_xor(ls, 32);
  if (isSplit) {
    if (hh == 0) {
      mpart[pidx * 128 + w * 32 + lc] = mL;
      lpart[pidx * 128 + w * 32 + lc] = lsT;
    }
#pragma unroll
    for (int r = 0; r < 16; ++r) {
      int q = (r & 3) + 8 * (r >> 2) + 4 * hh;
      int rp = w * 32 + q;
      Opart[(size_t)pidx * 8192 + rp * 64 + lc]      = f2bf(accO0[r]);
      Opart[(size_t)pidx * 8192 + rp * 64 + 32 + lc] = f2bf(accO1[r]);
    }
  } else {
    float inv = 1.f / lsT;
    alBuf[w][lc] = inv;
    asm volatile("s_waitcnt lgkmcnt(0)" ::: "memory");
    __builtin_amdgcn_sched_barrier(0);
#pragma unroll
    for (int r = 0; r < 16; ++r) {
      int q = (r & 3) + 8 * (r >> 2) + 4 * hh;
      float iv = alBuf[w][q];
      size_t row = (size_t)(b * T + qrow0 + q) * 1024 + hd * 64;
      o[row + lc]      = f2bf(accO0[r] * iv);
      o[row + 32 + lc] = f2bf(accO1[r] * iv);
    }
  }
}

// ---------------- merge split-KV partials into the attn buffer ----------------
// 262144 threads: e -> rowid = e>>3 (32 bh x 8 q8 x 128 r), c8 = e&7.
__global__ __launch_bounds__(256) void merge_kernel(const unsigned short* __restrict__ Opart,
                                                    const float* __restrict__ mpart,
                                                    const float* __restrict__ lpart,
                                                    unsigned short* __restrict__ o) {
  const int e = blockIdx.x * 256 + threadIdx.x;
  const int rowid = e >> 3, c8 = e & 7;
  const int bh = rowid >> 10, rem = rowid & 1023;
  const int q8 = rem >> 7, r = rem & 127;
  const int b = bh >> 4, hd = bh & 15;
  const int p0 = (((bh << 3) + q8) << 1);
  const float m0 = mpart[p0 * 128 + r], m1 = mpart[(p0 + 1) * 128 + r];
  const float l0 = lpart[p0 * 128 + r], l1 = lpart[(p0 + 1) * 128 + r];
  const float mS = fmaxf(m0, m1);
  const float e0 = __expf(m0 - mS), e1 = __expf(m1 - mS);
  const float inv = 1.f / (l0 * e0 + l1 * e1);
  const float f0 = e0 * inv, f1 = e1 * inv;
  const ushort8 a = *reinterpret_cast<const ushort8*>(Opart + (size_t)p0 * 8192 + r * 64 + c8 * 8);
  const ushort8 bb = *reinterpret_cast<const ushort8*>(Opart + (size_t)(p0 + 1) * 8192 + r * 64 + c8 * 8);
  ushort8 out;
#pragma unroll
  for (int j = 0; j < 8; ++j)
    out[j] = f2bf(bf2f(a[j]) * f0 + bf2f(bb[j]) * f1);
  const size_t row = (size_t)(b * 2048 + (q8 + 8) * 128 + r) * 1024 + hd * 64 + c8 * 8;
  *reinterpret_cast<ushort8*>(o + row) = out;
}

extern "C" void kernel_launch(void* const* d_in, const int* in_sizes, int n_in,
                              void* d_out, int out_size, void* d_ws, size_t ws_size,
                              hipStream_t stream) {
  const float* x     = (const float*)d_in[0];   // [2,2048,1024]
  const float* w_qkv = (const float*)d_in[1];   // [3072,1024]
  const float* w_out = (const float*)d_in[2];   // [1024,1024]
  float* out = (float*)d_out;                   // [2,2048,1024] fp32

  unsigned short* xb    = (unsigned short*)d_ws;                  // 4096*1024 elems
  unsigned short* wqkvb = xb    + (size_t)4096 * 1024;            // 3072*1024
  unsigned short* woutb = wqkvb + (size_t)3072 * 1024;            // 1024*1024
  unsigned short* qkv   = woutb + (size_t)1024 * 1024;            // 4096*3072
  unsigned short* attn  = qkv   + (size_t)4096 * 3072;            // 4096*1024

  // Partial buffers alias xb/wqkvb — dead after gemm1 consumes them.
  unsigned short* Opart = xb;                       // 512 tiles x 8192 = xb size
  float* mpart = (float*)wqkvb;                     // 512*128 fp32
  float* lpart = mpart + 512 * 128;

  cast3_kernel<<<dim3(2048), 256, 0, stream>>>(x,     4096 * 1024 / 4,
                                               w_qkv, 3072 * 1024 / 4,
                                               w_out, 1024 * 1024 / 4,
                                               xb, wqkvb, woutb);

  gemm_bt<true ><<<dim3(32, 24), 256, 0, stream>>>(xb,   wqkvb, (void*)qkv,  4096, 3072, 1024,
                                                   0.125f, 1024);
  attn_kernel  <<<dim3(768), 256, 0, stream>>>(qkv, attn, Opart, mpart, lpart);
  merge_kernel <<<dim3(1024), 256, 0, stream>>>(Opart, mpart, lpart, attn);
  gemm_bt<false><<<dim3(32,  8), 256, 0, stream>>>(attn, woutb, (void*)out, 4096, 1024, 1024,
                                                   1.0f, 0);
}

// Round 22
// 105.418 us; speedup vs baseline: 1.0061x; 1.0061x over previous
//
#include <hip/hip_runtime.h>
#include <hip/hip_bf16.h>

typedef __attribute__((ext_vector_type(8))) short bf16x8;
typedef __attribute__((ext_vector_type(8))) unsigned short ushort8;
typedef __attribute__((ext_vector_type(4))) float f32x4;
typedef __attribute__((ext_vector_type(16))) float f32x16;

typedef const __attribute__((address_space(1))) void gvoid;
typedef __attribute__((address_space(3))) void svoid;

__device__ __forceinline__ unsigned short f2bf(float f) {
  union { float f; unsigned int u; } v; v.f = f;
  unsigned int u = v.u;
  unsigned int r = (u + 0x7fffu + ((u >> 16) & 1u)) >> 16;
  return (unsigned short)r;
}
__device__ __forceinline__ float bf2f(unsigned short u) {
  union { unsigned int i; float f; } v; v.i = ((unsigned int)u) << 16; return v.f;
}

// ---------------- fused fp32 -> bf16 cast for all three inputs ----------------
__global__ void cast3_kernel(const float* __restrict__ a, int na4,
                             const float* __restrict__ b, int nb4,
                             const float* __restrict__ c, int nc4,
                             unsigned short* __restrict__ oa,
                             unsigned short* __restrict__ ob,
                             unsigned short* __restrict__ oc) {
  const int total = na4 + nb4 + nc4;
  for (int i = blockIdx.x * 256 + threadIdx.x; i < total; i += gridDim.x * 256) {
    const float* src; unsigned short* dst; int j = i;
    if (j < na4) { src = a; dst = oa; }
    else if (j < na4 + nb4) { j -= na4; src = b; dst = ob; }
    else { j -= na4 + nb4; src = c; dst = oc; }
    const float4 v = reinterpret_cast<const float4*>(src)[j];
    ushort4 o4;
    o4.x = f2bf(v.x); o4.y = f2bf(v.y); o4.z = f2bf(v.z); o4.w = f2bf(v.w);
    reinterpret_cast<ushort4*>(dst)[j] = o4;
  }
}

// ---------------- C[M][N] = A[M][K] * B[N][K]^T, bf16 in, fp32 acc ----------------
// 2-phase double-buffered 128x128 (converged config: BN=64, 256²-tile and
// counted-vmcnt variants all tested; neutral or regressed at this shape).
// cols < qcols get qscale in the epilogue (folds attn's 1/8 into q).
template<bool OUT_BF16>
__global__ __launch_bounds__(256) void gemm_bt(const unsigned short* __restrict__ A,
                                               const unsigned short* __restrict__ B,
                                               void* __restrict__ Cv,
                                               int M, int N, int K,
                                               float qscale, int qcols) {
  constexpr int BM = 128, BK = 32, TILE = BM * BK;
  __shared__ alignas(16) unsigned short As[2 * TILE];
  __shared__ alignas(16) unsigned short Bs[2 * TILE];
  const int tid = threadIdx.x;
  const int l  = tid & 63;
  const int w  = tid >> 6;
  const int wr = w >> 1, wc = w & 1;
  const int lr = l & 15, lg = l >> 4;
  const long tile_m = (long)blockIdx.x * BM;
  const long tile_n = (long)blockIdx.y * BM;

  const int c0 = tid, c1 = tid + 256;
  const unsigned short* pa0 = A + (tile_m + (c0 >> 2)) * (long)K + (c0 & 3) * 8;
  const unsigned short* pa1 = A + (tile_m + (c1 >> 2)) * (long)K + (c1 & 3) * 8;
  const unsigned short* pb0 = B + (tile_n + (c0 >> 2)) * (long)K + (c0 & 3) * 8;
  const unsigned short* pb1 = B + (tile_n + (c1 >> 2)) * (long)K + (c1 & 3) * 8;
  const int woff = w * 512;

  f32x4 acc[4][4] = {};

  __builtin_amdgcn_global_load_lds((gvoid*)pa0, (svoid*)(As + woff), 16, 0, 0);
  __builtin_amdgcn_global_load_lds((gvoid*)pa1, (svoid*)(As + 2048 + woff), 16, 0, 0);
  __builtin_amdgcn_global_load_lds((gvoid*)pb0, (svoid*)(Bs + woff), 16, 0, 0);
  __builtin_amdgcn_global_load_lds((gvoid*)pb1, (svoid*)(Bs + 2048 + woff), 16, 0, 0);
  __syncthreads();

  int cur = 0;
  for (int k0 = 0; k0 < K; k0 += BK) {
    if (k0 + BK < K) {
      unsigned short* An = As + (cur ^ 1) * TILE;
      unsigned short* Bn = Bs + (cur ^ 1) * TILE;
      __builtin_amdgcn_global_load_lds((gvoid*)(pa0 + k0 + BK), (svoid*)(An + woff), 16, 0, 0);
      __builtin_amdgcn_global_load_lds((gvoid*)(pa1 + k0 + BK), (svoid*)(An + 2048 + woff), 16, 0, 0);
      __builtin_amdgcn_global_load_lds((gvoid*)(pb0 + k0 + BK), (svoid*)(Bn + woff), 16, 0, 0);
      __builtin_amdgcn_global_load_lds((gvoid*)(pb1 + k0 + BK), (svoid*)(Bn + 2048 + woff), 16, 0, 0);
    }
    const unsigned short* AsC = As + cur * TILE;
    const unsigned short* BsC = Bs + cur * TILE;
    bf16x8 af[4], bfr[4];
#pragma unroll
    for (int m = 0; m < 4; ++m)
      af[m] = *reinterpret_cast<const bf16x8*>(AsC + (wr * 64 + m * 16 + lr) * BK + lg * 8);
#pragma unroll
    for (int n = 0; n < 4; ++n)
      bfr[n] = *reinterpret_cast<const bf16x8*>(BsC + (wc * 64 + n * 16 + lr) * BK + lg * 8);
#pragma unroll
    for (int m = 0; m < 4; ++m)
#pragma unroll
      for (int n = 0; n < 4; ++n)
        acc[m][n] = __builtin_amdgcn_mfma_f32_16x16x32_bf16(af[m], bfr[n], acc[m][n], 0, 0, 0);
    __syncthreads();
    cur ^= 1;
  }

#pragma unroll
  for (int m = 0; m < 4; ++m)
#pragma unroll
    for (int n = 0; n < 4; ++n)
#pragma unroll
      for (int r = 0; r < 4; ++r) {
        long row = tile_m + wr * 64 + m * 16 + lg * 4 + r;
        long col = tile_n + wc * 64 + n * 16 + lr;
        float sc = (col < qcols) ? qscale : 1.0f;
        if (OUT_BF16)
          reinterpret_cast<unsigned short*>(Cv)[row * N + col] = f2bf(acc[m][n][r] * sc);
        else
          reinterpret_cast<float*>(Cv)[row * N + col] = acc[m][n][r] * sc;
      }
}

// ---------------- causal flash attention: balanced KV-chunk jobs --------------
// 768 blocks x 256 threads. Job table: qtb 8..15 split into 2 KV chunks
// (partials merged by merge_kernel); qtb 0..7 whole. Swapped QK^T
// (mfma_32x32x16, A=K, B=Q) -> in-lane softmax + one shfl_xor(32);
// P->A-frags via v_cvt_pk_bf16_f32 + v_permlane32_swap; defer-max THR=8;
// wave-uniform needMask branch-hoist; s_setprio(1) around MFMA clusters.
// Q pre-scaled 0.125 in GEMM1 epilogue. K_lds slot^=k&7; Vt slot^=(d^(d>>3))&7.
__global__ __launch_bounds__(256, 2) void attn_kernel(const unsigned short* __restrict__ qkv,
                                                      unsigned short* __restrict__ o,
                                                      unsigned short* __restrict__ Opart,
                                                      float* __restrict__ mpart,
                                                      float* __restrict__ lpart) {
  constexpr int E = 3072, T = 2048;
  __shared__ alignas(16) unsigned short Ks[64 * 64];   // [k][d], slot ^= k&7
  __shared__ alignas(16) unsigned short Vt[64 * 64];   // [d][k], slot ^= (d^(d>>3))&7
  __shared__ float alBuf[4][32];

  static const int jq[24]  = {15,15, 7,14,14,13,13, 6,12,12,11,11, 5,10,10, 9, 9, 4, 8, 8, 3, 2, 1, 0};
  static const int jt0[24] = { 0,16, 0, 0,15, 0,14, 0, 0,13, 0,12, 0, 0,11, 0,10, 0, 0, 9, 0, 0, 0, 0};
  static const int jt1[24] = {16,32,16,15,30,14,28,14,13,26,12,24,12,11,22,10,20,10, 9,18, 8, 6, 4, 2};

  const int tid = threadIdx.x;
  const int l = tid & 63, w = tid >> 6;
  const int hh = l >> 5;       // lane half
  const int lc = l & 31;       // lane col: q-row (softmax) / d-col (O)
  int jj = blockIdx.x >> 5;
  if (jj >= 8 && jj < 16) jj = 23 - jj;     // reverse middle third for balance
  const int bh = blockIdx.x & 31;
  const int qtb = jq[jj], t0 = jt0[jj], t1 = jt1[jj];
  const bool isSplit = (qtb >= 8);
  const int part = (t0 != 0) ? 1 : 0;
  const int pidx = (((bh << 3) + (qtb - 8)) << 1) + part;
  const int b = bh >> 4, hd = bh & 15;
  const unsigned short* Qb = qkv + (size_t)b * T * E + hd * 64;
  const unsigned short* Kb = Qb + 1024;
  const unsigned short* Vb = Qb + 2048;

  const int qrow0 = qtb * 128 + w * 32;
  const int qg = qrow0 + lc;       // lane's q-row (global)

  // staging duty: 256 threads, 2 chunks each (rows 0..31 and 32..63)
  const int kr0 = tid >> 3, js0 = tid & 7;
  const int kr1 = kr0 + 32;
  const unsigned short* sK = Kb + (size_t)kr0 * E + js0 * 8;
  const unsigned short* sV = Vb + (size_t)kr0 * E + js0 * 8;
  const size_t tileStep = (size_t)64 * E;

  // Q fragments (B-operand): col=lc=q, k(d) = 16c + 8*hh + j
  bf16x8 aq[4];
#pragma unroll
  for (int c = 0; c < 4; ++c)
    aq[c] = *reinterpret_cast<const bf16x8*>(Qb + (size_t)qg * E + c * 16 + hh * 8);

  f32x16 accO0 = {}, accO1 = {};   // O[q][d]: frag0 d=lc, frag1 d=32+lc
  float mL = -1e30f, ls = 0.f;

  // prologue: tile t0 into regs
  ushort8 k0 = *reinterpret_cast<const ushort8*>(sK + (size_t)t0 * tileStep);
  ushort8 k1 = *reinterpret_cast<const ushort8*>(sK + (size_t)t0 * tileStep + 32 * E);
  ushort8 v0 = *reinterpret_cast<const ushort8*>(sV + (size_t)t0 * tileStep);
  ushort8 v1 = *reinterpret_cast<const ushort8*>(sV + (size_t)t0 * tileStep + 32 * E);

  for (int t = t0; t < t1; ++t) {
    __syncthreads();   // all waves done reading previous tile
    *reinterpret_cast<ushort8*>(Ks + kr0 * 64 + ((js0 ^ (kr0 & 7)) << 3)) = k0;
    *reinterpret_cast<ushort8*>(Ks + kr1 * 64 + ((js0 ^ (kr1 & 7)) << 3)) = k1;
#pragma unroll
    for (int e = 0; e < 8; ++e) {
      int d = js0 * 8 + e;
      int swz = (d ^ (d >> 3)) & 7;
      Vt[d * 64 + ((((kr0 >> 3) ^ swz) << 3) | (kr0 & 7))] = (unsigned short)v0[e];
      Vt[d * 64 + ((((kr1 >> 3) ^ swz) << 3) | (kr1 & 7))] = (unsigned short)v1[e];
    }
    __syncthreads();   // staging visible
    if (t + 1 < t1) {  // prefetch next tile into regs (lands during compute)
      const unsigned short* nK = sK + (size_t)(t + 1) * tileStep;
      const unsigned short* nV = sV + (size_t)(t + 1) * tileStep;
      k0 = *reinterpret_cast<const ushort8*>(nK);
      k1 = *reinterpret_cast<const ushort8*>(nK + 32 * E);
      v0 = *reinterpret_cast<const ushort8*>(nV);
      v1 = *reinterpret_cast<const ushort8*>(nV + 32 * E);
    }

    if (t * 64 > qrow0 + 31) continue;   // wave-uniform: tile fully masked

    // ---- S^T = K · Q^T : D[k][q], 2 frags (k 0..31, 32..63) ----
    f32x16 sT0 = {}, sT1 = {};
    __builtin_amdgcn_s_setprio(1);
#pragma unroll
    for (int c = 0; c < 4; ++c) {
      int sl = ((2 * c + hh) ^ (lc & 7)) << 3;
      bf16x8 ak0 = *reinterpret_cast<const bf16x8*>(Ks + lc * 64 + sl);
      bf16x8 ak1 = *reinterpret_cast<const bf16x8*>(Ks + (32 + lc) * 64 + sl);
      sT0 = __builtin_amdgcn_mfma_f32_32x32x16_bf16(ak0, aq[c], sT0, 0, 0, 0);
      sT1 = __builtin_amdgcn_mfma_f32_32x32x16_bf16(ak1, aq[c], sT1, 0, 0, 0);
    }
    __builtin_amdgcn_s_setprio(0);

    // ---- causal mask (wave-uniform branch) + row max ----
    const bool needMask = (t * 64 + 63) > qrow0;   // max_k vs wave's MIN q-row
    float pm = -1e30f;
    if (needMask) {
#pragma unroll
      for (int r = 0; r < 16; ++r) {
        int kb = t * 64 + (r & 3) + 8 * (r >> 2) + 4 * hh;
        float a0 = sT0[r], a1 = sT1[r];
        if (kb > qg) a0 = -1e30f;
        if (kb + 32 > qg) a1 = -1e30f;
        sT0[r] = a0; sT1[r] = a1;
        pm = fmaxf(pm, fmaxf(a0, a1));
      }
    } else {
#pragma unroll
      for (int r = 0; r < 16; ++r)
        pm = fmaxf(pm, fmaxf(sT0[r], sT1[r]));
    }
    pm = fmaxf(pm, __shfl_xor(pm, 32));   // lane pair shares the q-row

    // ---- defer-max (THR=8) ----
    if (__any(pm > mL + 8.f)) {
      float mn = fmaxf(mL, pm);
      float al = __expf(mL - mn);
      mL = mn;
      ls *= al;
      alBuf[w][lc] = al;
      asm volatile("s_waitcnt lgkmcnt(0)" ::: "memory");
      __builtin_amdgcn_sched_barrier(0);
#pragma unroll
      for (int r = 0; r < 16; ++r) {
        float alr = alBuf[w][(r & 3) + 8 * (r >> 2) + 4 * hh];
        accO0[r] *= alr;
        accO1[r] *= alr;
      }
    }

    // ---- P = exp(S-m); A-frags via cvt_pk + permlane32_swap ----
    bf16x8 pa[4];
    union U4 { unsigned int u[4]; bf16x8 v; };
#pragma unroll
    for (int n = 0; n < 2; ++n) {
      float p[16];
#pragma unroll
      for (int r = 0; r < 16; ++r) {
        float pv = __expf((n ? sT1[r] : sT0[r]) - mL);
        p[r] = pv;
        ls += pv;
      }
#pragma unroll
      for (int gg = 0; gg < 2; ++gg) {     // frag c' = 2n + gg, from p[8gg..8gg+7]
        unsigned int x0, x1, y0, y1;
        asm("v_cvt_pk_bf16_f32 %0, %1, %2" : "=v"(x0) : "v"(p[8 * gg + 0]), "v"(p[8 * gg + 1]));
        asm("v_cvt_pk_bf16_f32 %0, %1, %2" : "=v"(x1) : "v"(p[8 * gg + 2]), "v"(p[8 * gg + 3]));
        asm("v_cvt_pk_bf16_f32 %0, %1, %2" : "=v"(y0) : "v"(p[8 * gg + 4]), "v"(p[8 * gg + 5]));
        asm("v_cvt_pk_bf16_f32 %0, %1, %2" : "=v"(y1) : "v"(p[8 * gg + 6]), "v"(p[8 * gg + 7]));
        asm("v_permlane32_swap_b32 %0, %1" : "+v"(x0), "+v"(y0));
        asm("v_permlane32_swap_b32 %0, %1" : "+v"(x1), "+v"(y1));
        U4 fu;
        fu.u[0] = x0; fu.u[1] = x1; fu.u[2] = y0; fu.u[3] = y1;
        pa[2 * n + gg] = fu.v;
      }
    }

    // ---- O += P V : B[k][d] from Vt; frag m: d = 32m + lc ----
    __builtin_amdgcn_s_setprio(1);
#pragma unroll
    for (int cp = 0; cp < 4; ++cp) {
      int d0 = lc, d1 = 32 + lc;
      int sl0 = ((2 * cp + hh) ^ ((d0 ^ (d0 >> 3)) & 7)) << 3;
      int sl1 = ((2 * cp + hh) ^ ((d1 ^ (d1 >> 3)) & 7)) << 3;
      bf16x8 bv0 = *reinterpret_cast<const bf16x8*>(Vt + d0 * 64 + sl0);
      bf16x8 bv1 = *reinterpret_cast<const bf16x8*>(Vt + d1 * 64 + sl1);
      accO0 = __builtin_amdgcn_mfma_f32_32x32x16_bf16(pa[cp], bv0, accO0, 0, 0, 0);
      accO1 = __builtin_amdgcn_mfma_f32_32x32x16_bf16(pa[cp], bv1, accO1, 0, 0, 0);
    }
    __builtin_amdgcn_s_setprio(0);
  } // t

  // ---- finalize ----
  float lsT = ls + __shfl_xor(ls, 32);
  if (isSplit) {
    if (hh == 0) {
      mpart[pidx * 128 + w * 32 + lc] = mL;
      lpart[pidx * 128 + w * 32 + lc] = lsT;
    }
#pragma unroll
    for (int r = 0; r < 16; ++r) {
      int q = (r & 3) + 8 * (r >> 2) + 4 * hh;
      int rp = w * 32 + q;
      Opart[(size_t)pidx * 8192 + rp * 64 + lc]      = f2bf(accO0[r]);
      Opart[(size_t)pidx * 8192 + rp * 64 + 32 + lc] = f2bf(accO1[r]);
    }
  } else {
    float inv = 1.f / lsT;
    alBuf[w][lc] = inv;
    asm volatile("s_waitcnt lgkmcnt(0)" ::: "memory");
    __builtin_amdgcn_sched_barrier(0);
#pragma unroll
    for (int r = 0; r < 16; ++r) {
      int q = (r & 3) + 8 * (r >> 2) + 4 * hh;
      float iv = alBuf[w][q];
      size_t row = (size_t)(b * T + qrow0 + q) * 1024 + hd * 64;
      o[row + lc]      = f2bf(accO0[r] * iv);
      o[row + 32 + lc] = f2bf(accO1[r] * iv);
    }
  }
}

// ---------------- merge split-KV partials into the attn buffer ----------------
// 262144 threads: e -> rowid = e>>3 (32 bh x 8 q8 x 128 r), c8 = e&7.
__global__ __launch_bounds__(256) void merge_kernel(const unsigned short* __restrict__ Opart,
                                                    const float* __restrict__ mpart,
                                                    const float* __restrict__ lpart,
                                                    unsigned short* __restrict__ o) {
  const int e = blockIdx.x * 256 + threadIdx.x;
  const int rowid = e >> 3, c8 = e & 7;
  const int bh = rowid >> 10, rem = rowid & 1023;
  const int q8 = rem >> 7, r = rem & 127;
  const int b = bh >> 4, hd = bh & 15;
  const int p0 = (((bh << 3) + q8) << 1);
  const float m0 = mpart[p0 * 128 + r], m1 = mpart[(p0 + 1) * 128 + r];
  const float l0 = lpart[p0 * 128 + r], l1 = lpart[(p0 + 1) * 128 + r];
  const float mS = fmaxf(m0, m1);
  const float e0 = __expf(m0 - mS), e1 = __expf(m1 - mS);
  const float inv = 1.f / (l0 * e0 + l1 * e1);
  const float f0 = e0 * inv, f1 = e1 * inv;
  const ushort8 a = *reinterpret_cast<const ushort8*>(Opart + (size_t)p0 * 8192 + r * 64 + c8 * 8);
  const ushort8 bb = *reinterpret_cast<const ushort8*>(Opart + (size_t)(p0 + 1) * 8192 + r * 64 + c8 * 8);
  ushort8 out;
#pragma unroll
  for (int j = 0; j < 8; ++j)
    out[j] = f2bf(bf2f(a[j]) * f0 + bf2f(bb[j]) * f1);
  const size_t row = (size_t)(b * 2048 + (q8 + 8) * 128 + r) * 1024 + hd * 64 + c8 * 8;
  *reinterpret_cast<ushort8*>(o + row) = out;
}

extern "C" void kernel_launch(void* const* d_in, const int* in_sizes, int n_in,
                              void* d_out, int out_size, void* d_ws, size_t ws_size,
                              hipStream_t stream) {
  const float* x     = (const float*)d_in[0];   // [2,2048,1024]
  const float* w_qkv = (const float*)d_in[1];   // [3072,1024]
  const float* w_out = (const float*)d_in[2];   // [1024,1024]
  float* out = (float*)d_out;                   // [2,2048,1024] fp32

  unsigned short* xb    = (unsigned short*)d_ws;                  // 4096*1024 elems
  unsigned short* wqkvb = xb    + (size_t)4096 * 1024;            // 3072*1024
  unsigned short* woutb = wqkvb + (size_t)3072 * 1024;            // 1024*1024
  unsigned short* qkv   = woutb + (size_t)1024 * 1024;            // 4096*3072
  unsigned short* attn  = qkv   + (size_t)4096 * 3072;            // 4096*1024

  // Partial buffers alias xb/wqkvb — dead after gemm1 consumes them.
  unsigned short* Opart = xb;                       // 512 tiles x 8192 = xb size
  float* mpart = (float*)wqkvb;                     // 512*128 fp32
  float* lpart = mpart + 512 * 128;

  cast3_kernel<<<dim3(2048), 256, 0, stream>>>(x,     4096 * 1024 / 4,
                                               w_qkv, 3072 * 1024 / 4,
                                               w_out, 1024 * 1024 / 4,
                                               xb, wqkvb, woutb);

  gemm_bt<true ><<<dim3(32, 24), 256, 0, stream>>>(xb,   wqkvb, (void*)qkv,  4096, 3072, 1024,
                                                   0.125f, 1024);
  attn_kernel  <<<dim3(768), 256, 0, stream>>>(qkv, attn, Opart, mpart, lpart);
  merge_kernel <<<dim3(1024), 256, 0, stream>>>(Opart, mpart, lpart, attn);
  gemm_bt<false><<<dim3(32,  8), 256, 0, stream>>>(attn, woutb, (void*)out, 4096, 1024, 1024,
                                                   1.0f, 0);
}